// Round 2
// baseline (546.469 us; speedup 1.0000x reference)
//
#include <hip/hip_runtime.h>
#include <hip/hip_bf16.h>

// GLinear: out[p,o,d] = W_{seg(d)}[o,i] * x[p,i,d] + x[p,o,d]
// P=8192, C=256, D=16. seg: d=0->W00, d in 1..6->W10, d in 7..15->W11.
// bf16 MFMA (16x16x32) with fp32 accumulate; residual added in exact fp32.
// Memory-bound: floor ~42us (268MB @ 6.3TB/s).

#define C_DIM   256
#define D_DIM   16
#define P_TILE  16
#define KC      64     // i-chunk staged per barrier
#define LDS_ROW 72     // bf16 elems per (p,d) row: 64 data + 8 pad

typedef __attribute__((ext_vector_type(8))) short  short8v;   // 8 x bf16 MFMA frag
typedef __attribute__((ext_vector_type(4))) float  float4v;
typedef __attribute__((ext_vector_type(4))) unsigned int uint4v;

// Manual RNE fp32->bf16, packed pair into a dword (lo in bits[15:0]).
// __hip_bfloat162 is not trivially copyable on this ROCm -> no bit_cast.
__device__ __forceinline__ unsigned int pack_bf16x2(float lo, float hi) {
    unsigned int ul = __builtin_bit_cast(unsigned int, lo);
    unsigned int uh = __builtin_bit_cast(unsigned int, hi);
    ul = (ul + 0x7fffu + ((ul >> 16) & 1u)) >> 16;
    uh = (uh + 0x7fffu + ((uh >> 16) & 1u));
    return (ul & 0xffffu) | (uh & 0xffff0000u);
}

__device__ __forceinline__ short8v load_w_frag(const float* __restrict__ W, int row, int col) {
    const float* p = W + (size_t)row * C_DIM + col;
    float4v a = *(const float4v*)p;
    float4v b = *(const float4v*)(p + 4);
    uint4v u;
    u.x = pack_bf16x2(a.x, a.y);
    u.y = pack_bf16x2(a.z, a.w);
    u.z = pack_bf16x2(b.x, b.y);
    u.w = pack_bf16x2(b.z, b.w);
    return __builtin_bit_cast(short8v, u);
}

__global__ __launch_bounds__(256, 4) void glinear_kernel(
    const float* __restrict__ x, const float* __restrict__ W00,
    const float* __restrict__ W10, const float* __restrict__ W11,
    float* __restrict__ out)
{
    // XOR-swizzled i-groups: elem (p,i,d) at
    // row = p*16+d, col = ((i>>3)^(p&7))*8 + (i&7)
    __shared__ unsigned short ls[P_TILE * D_DIM * LDS_ROW];   // 36864 B

    const int t    = threadIdx.x;
    const int lane = t & 63;
    const int w    = t >> 6;        // wave 0..3
    const int opair = w >> 1;       // o-tile pair {0,1} or {2,3}
    const int whalf = w & 1;        // d-half: 0 -> d 0..7, 1 -> d 8..15

    const int bx    = blockIdx.x;
    const int ogrp  = bx & 3;       // consecutive blocks share p-tile (L3 reuse of x)
    const int ptile = bx >> 2;
    const int pbase = ptile * P_TILE;
    const int obase = ogrp * 64;

    float4v acc[2][8];
    const float4v fzero = {0.f, 0.f, 0.f, 0.f};
    #pragma unroll
    for (int a = 0; a < 2; ++a)
        #pragma unroll
        for (int b = 0; b < 8; ++b) acc[a][b] = fzero;

    // staging coords (fixed per thread): thread covers (d4, i pair, p0+2*it)
    const int d4    = t & 3;
    const int ip    = (t >> 2) & 31;
    const int p0    = t >> 7;           // 0..1
    const int i_loc = ip * 2;           // even i in 0..62

    // compute coords
    const int lm   = lane & 15;         // o row for A / p for B and C
    const int quad = lane >> 4;

    for (int ic = 0; ic < 4; ++ic) {
        const int ibase = ic * KC;

        // ---- stage x chunk: [16p x 64i x 16d] fp32 -> bf16 LDS [p][d][i] ----
        #pragma unroll
        for (int it = 0; it < 8; ++it) {
            const int p = p0 + it * 2;
            const float* src = x + ((size_t)(pbase + p) * C_DIM + (ibase + i_loc)) * D_DIM + d4 * 4;
            float4v a = *(const float4v*)src;            // i_loc,   d4*4..+3
            float4v b = *(const float4v*)(src + D_DIM);  // i_loc+1, d4*4..+3
            const int g = (i_loc >> 3) ^ (p & 7);
            const int e = i_loc & 7;
            const int base = (p * D_DIM + d4 * 4) * LDS_ROW + g * 8 + e;
            #pragma unroll
            for (int dj = 0; dj < 4; ++dj) {
                unsigned int u = pack_bf16x2(a[dj], b[dj]);  // (i, i+1) pair
                *(unsigned int*)(&ls[base + dj * LDS_ROW]) = u;
            }
        }
        __syncthreads();

        // ---- compute: 2 k-steps of 32 ----
        #pragma unroll
        for (int ks = 0; ks < 2; ++ks) {
            const int col = ibase + ks * 32 + quad * 8;
            const int gq  = ((ks * 4 + quad) ^ (lm & 7));
            const unsigned short* brow = &ls[lm * D_DIM * LDS_ROW + gq * 8];

            if (whalf == 0) {
                short8v a0[2], a1[2], a2[2];
                #pragma unroll
                for (int ot = 0; ot < 2; ++ot) {
                    const int orow = obase + (opair * 2 + ot) * 16 + lm;
                    a0[ot] = load_w_frag(W00, orow, col);
                    a1[ot] = load_w_frag(W10, orow, col);
                    a2[ot] = load_w_frag(W11, orow, col);
                }
                #pragma unroll
                for (int dd = 0; dd < 8; ++dd) {     // d = dd
                    short8v bf = *(const short8v*)(brow + dd * LDS_ROW);
                    if (dd == 0) {
                        acc[0][dd] = __builtin_amdgcn_mfma_f32_16x16x32_bf16(a0[0], bf, acc[0][dd], 0, 0, 0);
                        acc[1][dd] = __builtin_amdgcn_mfma_f32_16x16x32_bf16(a0[1], bf, acc[1][dd], 0, 0, 0);
                    } else if (dd <= 6) {
                        acc[0][dd] = __builtin_amdgcn_mfma_f32_16x16x32_bf16(a1[0], bf, acc[0][dd], 0, 0, 0);
                        acc[1][dd] = __builtin_amdgcn_mfma_f32_16x16x32_bf16(a1[1], bf, acc[1][dd], 0, 0, 0);
                    } else {
                        acc[0][dd] = __builtin_amdgcn_mfma_f32_16x16x32_bf16(a2[0], bf, acc[0][dd], 0, 0, 0);
                        acc[1][dd] = __builtin_amdgcn_mfma_f32_16x16x32_bf16(a2[1], bf, acc[1][dd], 0, 0, 0);
                    }
                }
            } else {
                short8v a2[2];
                #pragma unroll
                for (int ot = 0; ot < 2; ++ot) {
                    const int orow = obase + (opair * 2 + ot) * 16 + lm;
                    a2[ot] = load_w_frag(W11, orow, col);
                }
                #pragma unroll
                for (int dd = 0; dd < 8; ++dd) {     // d = 8+dd, always W11
                    short8v bf = *(const short8v*)(brow + (8 + dd) * LDS_ROW);
                    acc[0][dd] = __builtin_amdgcn_mfma_f32_16x16x32_bf16(a2[0], bf, acc[0][dd], 0, 0, 0);
                    acc[1][dd] = __builtin_amdgcn_mfma_f32_16x16x32_bf16(a2[1], bf, acc[1][dd], 0, 0, 0);
                }
            }
        }
        __syncthreads();
    }

    // ---- epilogue: acc (C/D layout col=lane&15=p, row=quad*4+r=o) + residual ----
    #pragma unroll
    for (int ot = 0; ot < 2; ++ot) {
        #pragma unroll
        for (int r = 0; r < 4; ++r) {
            const int o = obase + (opair * 2 + ot) * 16 + quad * 4 + r;
            const size_t off = ((size_t)(pbase + lm) * C_DIM + o) * D_DIM + whalf * 8;
            #pragma unroll
            for (int h = 0; h < 2; ++h) {
                float4v v;
                v.x = acc[ot][h * 4 + 0][r];
                v.y = acc[ot][h * 4 + 1][r];
                v.z = acc[ot][h * 4 + 2][r];
                v.w = acc[ot][h * 4 + 3][r];
                float4v xr = *(const float4v*)(x + off + h * 4);
                *(float4v*)(out + off + h * 4) = v + xr;
            }
        }
    }
}

extern "C" void kernel_launch(void* const* d_in, const int* in_sizes, int n_in,
                              void* d_out, int out_size, void* d_ws, size_t ws_size,
                              hipStream_t stream) {
    const float* x   = (const float*)d_in[0];
    const float* W00 = (const float*)d_in[1];
    const float* W10 = (const float*)d_in[2];
    const float* W11 = (const float*)d_in[3];
    float* out = (float*)d_out;

    dim3 grid(2048);   // 512 p-tiles * 4 o-groups
    dim3 block(256);
    hipLaunchKernelGGL(glinear_kernel, grid, block, 0, stream, x, W00, W10, W11, out);
}

// Round 3
// 484.761 us; speedup vs baseline: 1.1273x; 1.1273x over previous
//
#include <hip/hip_runtime.h>
#include <hip/hip_bf16.h>

// GLinear: out[p,o,d] = W_{seg(d)}[o,i] * x[p,i,d] + x[p,o,d]
// P=8192, C=256, D=16. seg: d=0->W00, d in 1..6->W10, d in 7..15->W11.
// bf16 MFMA (16x16x32), fp32 accumulate, fp32 residual.
// R2 post-mortem: WRITE 774MB (5.8x) from scattered 16B epilogue stores,
// FETCH 705MB from 4x staging duplication across XCDs. This version:
//  - sibling blocks (same p-tile) mapped to same XCD (bx,bx+8,bx+16,bx+24)
//  - epilogue transposed through LDS -> 1KB-contiguous loads/stores
//  - bf16 pack via single v_perm_b32 (truncate; 5.6x absmax margin)

#define C_DIM   256
#define D_DIM   16
#define P_TILE  16
#define KC      64
#define LDS_ROW 72     // bf16 elems per (p,d) row: 64 data + 8 pad

typedef __attribute__((ext_vector_type(8))) short  short8v;
typedef __attribute__((ext_vector_type(4))) float  float4v;
typedef __attribute__((ext_vector_type(4))) unsigned int uint4v;

// Truncating fp32->bf16 pair pack: one v_perm_b32.
// dst = { lo.b2, lo.b3, hi.b2, hi.b3 }
__device__ __forceinline__ unsigned int pack_bf16x2(float lo, float hi) {
    return __builtin_amdgcn_perm(__builtin_bit_cast(unsigned int, hi),
                                 __builtin_bit_cast(unsigned int, lo),
                                 0x07060302u);
}

__device__ __forceinline__ short8v load_w_frag(const float* __restrict__ W, int row, int col) {
    const float* p = W + (size_t)row * C_DIM + col;
    float4v a = *(const float4v*)p;
    float4v b = *(const float4v*)(p + 4);
    uint4v u;
    u.x = pack_bf16x2(a.x, a.y);
    u.y = pack_bf16x2(a.z, a.w);
    u.z = pack_bf16x2(b.x, b.y);
    u.w = pack_bf16x2(b.z, b.w);
    return __builtin_bit_cast(short8v, u);
}

__global__ __launch_bounds__(256, 4) void glinear_kernel(
    const float* __restrict__ x, const float* __restrict__ W00,
    const float* __restrict__ W10, const float* __restrict__ W11,
    float* __restrict__ out)
{
    // shared memory, aliased:
    //  K-loop:  ushort stage[16p][16d][72]  (36864 B)
    //  epilogue: float  ep[16p][512]        (32768 B), phased by o-half
    __shared__ __align__(16) char smraw[P_TILE * D_DIM * LDS_ROW * 2];
    unsigned short* ls = (unsigned short*)smraw;
    float* ep = (float*)smraw;

    const int t    = threadIdx.x;
    const int lane = t & 63;
    const int w    = t >> 6;
    const int opair = w >> 1;       // o-tile pair {0,1} or {2,3}
    const int whalf = w & 1;        // d-half

    // sibling blocks (same p-tile, ogrp 0..3) at bx, bx+8, bx+16, bx+24
    // -> same XCD under round-robin bx%8 dispatch -> L2 reuse of x tile.
    const int bx    = blockIdx.x;
    const int ogrp  = (bx >> 3) & 3;
    const int ptile = (bx & 7) | ((bx >> 5) << 3);
    const int pbase = ptile * P_TILE;
    const int obase = ogrp * 64;

    float4v acc[2][8];
    const float4v fzero = {0.f, 0.f, 0.f, 0.f};
    #pragma unroll
    for (int a = 0; a < 2; ++a)
        #pragma unroll
        for (int b = 0; b < 8; ++b) acc[a][b] = fzero;

    // staging coords
    const int d4    = t & 3;
    const int ip    = (t >> 2) & 31;
    const int p0    = t >> 7;
    const int i_loc = ip * 2;

    // compute coords
    const int lm   = lane & 15;
    const int quad = lane >> 4;

    for (int ic = 0; ic < 4; ++ic) {
        const int ibase = ic * KC;

        // ---- stage x chunk: [16p x 64i x 16d] fp32 -> bf16 LDS [p][d][i] ----
        #pragma unroll
        for (int it = 0; it < 8; ++it) {
            const int p = p0 + it * 2;
            const float* src = x + ((size_t)(pbase + p) * C_DIM + (ibase + i_loc)) * D_DIM + d4 * 4;
            float4v a = *(const float4v*)src;
            float4v b = *(const float4v*)(src + D_DIM);
            const int g = (i_loc >> 3) ^ (p & 7);
            const int e = i_loc & 7;
            const int base = (p * D_DIM + d4 * 4) * LDS_ROW + g * 8 + e;
            #pragma unroll
            for (int dj = 0; dj < 4; ++dj) {
                unsigned int u = pack_bf16x2(a[dj], b[dj]);
                *(unsigned int*)(&ls[base + dj * LDS_ROW]) = u;
            }
        }
        __syncthreads();

        // ---- compute: 2 k-steps of 32 ----
        #pragma unroll
        for (int ks = 0; ks < 2; ++ks) {
            const int col = ibase + ks * 32 + quad * 8;
            const int gq  = ((ks * 4 + quad) ^ (lm & 7));
            const unsigned short* brow = &ls[lm * D_DIM * LDS_ROW + gq * 8];

            if (whalf == 0) {
                short8v a0[2], a1[2], a2[2];
                #pragma unroll
                for (int ot = 0; ot < 2; ++ot) {
                    const int orow = obase + (opair * 2 + ot) * 16 + lm;
                    a0[ot] = load_w_frag(W00, orow, col);
                    a1[ot] = load_w_frag(W10, orow, col);
                    a2[ot] = load_w_frag(W11, orow, col);
                }
                #pragma unroll
                for (int dd = 0; dd < 8; ++dd) {
                    short8v bf = *(const short8v*)(brow + dd * LDS_ROW);
                    if (dd == 0) {
                        acc[0][dd] = __builtin_amdgcn_mfma_f32_16x16x32_bf16(a0[0], bf, acc[0][dd], 0, 0, 0);
                        acc[1][dd] = __builtin_amdgcn_mfma_f32_16x16x32_bf16(a0[1], bf, acc[1][dd], 0, 0, 0);
                    } else if (dd <= 6) {
                        acc[0][dd] = __builtin_amdgcn_mfma_f32_16x16x32_bf16(a1[0], bf, acc[0][dd], 0, 0, 0);
                        acc[1][dd] = __builtin_amdgcn_mfma_f32_16x16x32_bf16(a1[1], bf, acc[1][dd], 0, 0, 0);
                    } else {
                        acc[0][dd] = __builtin_amdgcn_mfma_f32_16x16x32_bf16(a2[0], bf, acc[0][dd], 0, 0, 0);
                        acc[1][dd] = __builtin_amdgcn_mfma_f32_16x16x32_bf16(a2[1], bf, acc[1][dd], 0, 0, 0);
                    }
                }
            } else {
                short8v a2[2];
                #pragma unroll
                for (int ot = 0; ot < 2; ++ot) {
                    const int orow = obase + (opair * 2 + ot) * 16 + lm;
                    a2[ot] = load_w_frag(W11, orow, col);
                }
                #pragma unroll
                for (int dd = 0; dd < 8; ++dd) {
                    short8v bf = *(const short8v*)(brow + (8 + dd) * LDS_ROW);
                    acc[0][dd] = __builtin_amdgcn_mfma_f32_16x16x32_bf16(a2[0], bf, acc[0][dd], 0, 0, 0);
                    acc[1][dd] = __builtin_amdgcn_mfma_f32_16x16x32_bf16(a2[1], bf, acc[1][dd], 0, 0, 0);
                }
            }
        }
        __syncthreads();
    }

    // ---- epilogue via LDS, phased by o-half (32 o per phase) ----
    // writer: acc[ot][dd][r] = out_mm(p=lm, o=obase+ph*32+ot*16+quad*4+r, d=whalf*8+dd)
    // LDS chunk c = o_local*4 + whalf*2 + h (16B units), swizzled c^=lm&7
    #pragma unroll
    for (int ph = 0; ph < 2; ++ph) {
        if (opair == ph) {
            #pragma unroll
            for (int ot = 0; ot < 2; ++ot) {
                #pragma unroll
                for (int r = 0; r < 4; ++r) {
                    const int o_local = ot * 16 + quad * 4 + r;
                    #pragma unroll
                    for (int h = 0; h < 2; ++h) {
                        float4v v;
                        v.x = acc[ot][h * 4 + 0][r];
                        v.y = acc[ot][h * 4 + 1][r];
                        v.z = acc[ot][h * 4 + 2][r];
                        v.w = acc[ot][h * 4 + 3][r];
                        const int c  = o_local * 4 + whalf * 2 + h;
                        const int cs = c ^ (lm & 7);
                        *(float4v*)(ep + lm * 512 + cs * 4) = v;
                    }
                }
            }
        }
        __syncthreads();

        // readers: 2048 chunks (16 rows x 128), 8 per thread, wave-contiguous
        #pragma unroll
        for (int j = 0; j < 8; ++j) {
            const int G   = j * 256 + t;
            const int row = G >> 7;
            const int c   = G & 127;
            const int cs  = c ^ (row & 7);
            float4v v = *(const float4v*)(ep + row * 512 + cs * 4);
            const size_t goff = (size_t)(pbase + row) * (C_DIM * D_DIM)
                              + (size_t)(obase + ph * 32) * D_DIM + c * 4;
            float4v xr = *(const float4v*)(x + goff);
            *(float4v*)(out + goff) = v + xr;
        }
        __syncthreads();
    }
}

extern "C" void kernel_launch(void* const* d_in, const int* in_sizes, int n_in,
                              void* d_out, int out_size, void* d_ws, size_t ws_size,
                              hipStream_t stream) {
    const float* x   = (const float*)d_in[0];
    const float* W00 = (const float*)d_in[1];
    const float* W10 = (const float*)d_in[2];
    const float* W11 = (const float*)d_in[3];
    float* out = (float*)d_out;

    dim3 grid(2048);
    dim3 block(256);
    hipLaunchKernelGGL(glinear_kernel, grid, block, 0, stream, x, W00, W10, W11, out);
}

// Round 4
// 315.821 us; speedup vs baseline: 1.7303x; 1.5349x over previous
//
#include <hip/hip_runtime.h>
#include <hip/hip_bf16.h>

// GLinear: out[p,o,d] = W_{seg(d)}[o,i] * x[p,i,d] + x[p,o,d]
// P=8192, C=256, D=16. seg: d=0->W00, 1..6->W10, 7..15->W11.
// R3 post-mortem: __launch_bounds__(256,4) => 128-reg cap => scratch spill
// (~566MB deterministic WRITE excess, L2 thrash). R4:
//  - 512-thr block covers 16p x 256o: x staged exactly once (no XCD dup)
//  - __launch_bounds__(512,1): full register budget, no spill
//  - MFMA operands swapped (A=x, B=W) => C/D row=p,col=o => direct float4
//    stores along d, lanes span consecutive o => full-line writes, no LDS epi
//  - RNE bf16 pack for x staging; trunc (v_perm) pack for W

#define C_DIM   256
#define D_DIM   16
#define P_TILE  16
#define KC      64
#define LDS_ROW 72     // bf16 elems per (p,d) row: 64 data + 8 pad

typedef __attribute__((ext_vector_type(8))) short  short8v;
typedef __attribute__((ext_vector_type(4))) float  float4v;
typedef __attribute__((ext_vector_type(4))) unsigned int uint4v;

// RNE fp32->bf16 pair pack (manual; __hip_bfloat162 not bit_castable here)
__device__ __forceinline__ unsigned int pack_bf16x2_rne(float lo, float hi) {
    unsigned int ul = __builtin_bit_cast(unsigned int, lo);
    unsigned int uh = __builtin_bit_cast(unsigned int, hi);
    ul = (ul + 0x7fffu + ((ul >> 16) & 1u)) >> 16;
    uh = (uh + 0x7fffu + ((uh >> 16) & 1u));
    return (ul & 0xffffu) | (uh & 0xffff0000u);
}

// Truncating pack: single v_perm_b32 (W path; error budget has 2.8x margin)
__device__ __forceinline__ unsigned int pack_bf16x2_tr(float lo, float hi) {
    return __builtin_amdgcn_perm(__builtin_bit_cast(unsigned int, hi),
                                 __builtin_bit_cast(unsigned int, lo),
                                 0x07060302u);
}

__device__ __forceinline__ short8v load_w_frag(const float* __restrict__ W, int row, int col) {
    const float* p = W + (size_t)row * C_DIM + col;
    float4v a = *(const float4v*)p;
    float4v b = *(const float4v*)(p + 4);
    uint4v u;
    u.x = pack_bf16x2_tr(a.x, a.y);
    u.y = pack_bf16x2_tr(a.z, a.w);
    u.z = pack_bf16x2_tr(b.x, b.y);
    u.w = pack_bf16x2_tr(b.z, b.w);
    return __builtin_bit_cast(short8v, u);
}

__global__ __launch_bounds__(512, 1) void glinear_kernel(
    const float* __restrict__ x, const float* __restrict__ W00,
    const float* __restrict__ W10, const float* __restrict__ W11,
    float* __restrict__ out)
{
    // bf16 x-tile: elem (p,i,d) at row = p*16+d, col = ((i>>3)^(p&7))*8 + (i&7)
    __shared__ __align__(16) unsigned short ls[P_TILE * D_DIM * LDS_ROW]; // 36864 B

    const int t    = threadIdx.x;
    const int lane = t & 63;
    const int w    = t >> 6;          // wave 0..7 -> o in [32w, 32w+32)
    const int lm   = lane & 15;
    const int quad = lane >> 4;

    const int pbase = blockIdx.x * P_TILE;

    float4v acc[2][16];
    const float4v fzero = {0.f, 0.f, 0.f, 0.f};
    #pragma unroll
    for (int a = 0; a < 2; ++a)
        #pragma unroll
        for (int b = 0; b < 16; ++b) acc[a][b] = fzero;

    // staging coords: 512 threads cover 16p x 64i x 16d per chunk
    const int d4    = t & 3;              // d-group of 4
    const int ip    = (t >> 2) & 31;      // i-pair index
    const int pq    = t >> 7;             // 0..3
    const int i_loc = ip * 2;

    const int orow0 = w * 32 + lm;        // W rows for B-fragments
    const int orow1 = w * 32 + 16 + lm;

    for (int ic = 0; ic < 4; ++ic) {
        const int ibase = ic * KC;

        // ---- stage x chunk fp32 -> bf16 LDS [p][d][i] ----
        #pragma unroll
        for (int it = 0; it < 4; ++it) {
            const int p = pq + it * 4;
            const float* src = x + ((size_t)(pbase + p) * C_DIM + (ibase + i_loc)) * D_DIM + d4 * 4;
            float4v a = *(const float4v*)src;            // i_loc
            float4v b = *(const float4v*)(src + D_DIM);  // i_loc+1
            const int g = (i_loc >> 3) ^ (p & 7);
            const int e = i_loc & 7;
            const int base = (p * D_DIM + d4 * 4) * LDS_ROW + g * 8 + e;
            #pragma unroll
            for (int dj = 0; dj < 4; ++dj) {
                *(unsigned int*)(&ls[base + dj * LDS_ROW]) = pack_bf16x2_rne(a[dj], b[dj]);
            }
        }
        __syncthreads();

        // ---- compute: 2 k-steps of 32 ----
        #pragma unroll
        for (int ks = 0; ks < 2; ++ks) {
            const int col = ibase + ks * 32 + quad * 8;
            const int gq  = ((ks * 4 + quad) ^ (lm & 7));
            const unsigned short* brow = &ls[lm * D_DIM * LDS_ROW + gq * 8];

            short8v f00_0 = load_w_frag(W00, orow0, col);
            short8v f00_1 = load_w_frag(W00, orow1, col);
            short8v f10_0 = load_w_frag(W10, orow0, col);
            short8v f10_1 = load_w_frag(W10, orow1, col);
            short8v f11_0 = load_w_frag(W11, orow0, col);
            short8v f11_1 = load_w_frag(W11, orow1, col);

            #pragma unroll
            for (int dd = 0; dd < 16; ++dd) {
                short8v xf = *(const short8v*)(brow + dd * LDS_ROW);
                short8v w0 = (dd == 0) ? f00_0 : (dd <= 6) ? f10_0 : f11_0;
                short8v w1 = (dd == 0) ? f00_1 : (dd <= 6) ? f10_1 : f11_1;
                // A = x (m=p), B = W (n=o) -> D row=p(quad*4+reg), col=o(lane&15)
                acc[0][dd] = __builtin_amdgcn_mfma_f32_16x16x32_bf16(xf, w0, acc[0][dd], 0, 0, 0);
                acc[1][dd] = __builtin_amdgcn_mfma_f32_16x16x32_bf16(xf, w1, acc[1][dd], 0, 0, 0);
            }
        }
        __syncthreads();
    }

    // ---- epilogue: direct stores. lane -> (p = quad*4+r, o = w*32+ot*16+lm) ----
    // float4 along d; lanes of a quad span 16 consecutive o (64B-line stride),
    // 4 g-stores complete each 64B line back-to-back.
    #pragma unroll
    for (int ot = 0; ot < 2; ++ot) {
        const int o = w * 32 + ot * 16 + lm;
        #pragma unroll
        for (int r = 0; r < 4; ++r) {
            const int p = pbase + quad * 4 + r;
            const size_t off = (size_t)p * (C_DIM * D_DIM) + (size_t)o * D_DIM;
            #pragma unroll
            for (int g = 0; g < 4; ++g) {
                float4v v;
                v.x = acc[ot][g * 4 + 0][r];
                v.y = acc[ot][g * 4 + 1][r];
                v.z = acc[ot][g * 4 + 2][r];
                v.w = acc[ot][g * 4 + 3][r];
                float4v xr = *(const float4v*)(x + off + g * 4);
                *(float4v*)(out + off + g * 4) = v + xr;
            }
        }
    }
}

extern "C" void kernel_launch(void* const* d_in, const int* in_sizes, int n_in,
                              void* d_out, int out_size, void* d_ws, size_t ws_size,
                              hipStream_t stream) {
    const float* x   = (const float*)d_in[0];
    const float* W00 = (const float*)d_in[1];
    const float* W10 = (const float*)d_in[2];
    const float* W11 = (const float*)d_in[3];
    float* out = (float*)d_out;

    dim3 grid(512);    // one block per 16-row p-tile; x staged exactly once
    dim3 block(512);
    hipLaunchKernelGGL(glinear_kernel, grid, block, 0, stream, x, W00, W10, W11, out);
}